// Round 5
// baseline (223.925 us; speedup 1.0000x reference)
//
#include <hip/hip_runtime.h>
#include <hip/hip_bf16.h>
#include <math.h>

// IntegralTransform via bf16 MFMA (16x16x32), v4 "transposed chain":
//  - v3 counters: VALUBusy 77%, MfmaUtil 12%, HBM 3%, occ 31% (LDS-capped
//    4 blk/CU), 1.6M LDS bank-conflict cycles. Bottleneck = VALU issue +
//    serial LDS round-trips between MLP layers.
//  - v4 computes h^T throughout: D[m=hidden, n=edge]. The SAME wpack frags
//    serve as A-operands (A/B lane layouts are mutual transposes); fy gather
//    unchanged. Inter-layer transpose = 2-step register butterfly across
//    quads (shfl_xor 32 then 16 + cndmask), NO LDS buffer: ldsB deleted
//    (LDS 38.9K -> 20.9K), bank conflicts gone, no lgkmcnt serial waits.
//  - b1 folded into MFMA spare slot k=38 (B-side gets 1.0). b2/b3 in a small
//    LDS table (re-read per point via the woff anti-LICM barrier).
//  - epilogue in transposed layout: fy via 2 x u64 loads (was 16 x u16);
//    reduce over c16 lanes (shfl_xor 1/2/4/8); 4 lanes store 2 float4 each.
//  - gelu on float2 ext-vectors to encourage v_pk_*_f32.
//  (Round-4 resubmit: previous bench died on container infra, no data.)

typedef __attribute__((ext_vector_type(8))) short short8;
typedef __attribute__((ext_vector_type(4))) float floatx4;
typedef __attribute__((ext_vector_type(2))) float f32x2;
typedef __attribute__((ext_vector_type(4))) unsigned short ushort4v;

__device__ __forceinline__ unsigned short bf16rne(float f) {
    unsigned int u = __float_as_uint(f);
    u += 0x7fffu + ((u >> 16) & 1u);
    return (unsigned short)(u >> 16);
}
__device__ __forceinline__ unsigned int pk2(float a, float b) {
    union { __hip_bfloat162 h; unsigned int u; } cv;
    cv.h = __float22bfloat162_rn(make_float2(a, b));
    return cv.u;
}
__device__ __forceinline__ float bf16f(unsigned short u) {
    return __uint_as_float(((unsigned int)u) << 16);
}
// tanh-form gelu on a pair: x*(1 - 1/(exp(2*0.7978845608*x*(1+0.044715x^2))+1))
__device__ __forceinline__ f32x2 gelu2(f32x2 x) {
    f32x2 t = x * x;
    f32x2 u = x * (0.044715f * t + 1.0f);
    float ex = __expf(1.5957691f * u.x);
    float ey = __expf(1.5957691f * u.y);
    f32x2 r;
    r.x = __builtin_amdgcn_rcpf(ex + 1.0f);
    r.y = __builtin_amdgcn_rcpf(ey + 1.0f);
    return x - x * r;
}

#define MFMA16(a, b, c) __builtin_amdgcn_mfma_f32_16x16x32_bf16(a, b, c, 0, 0, 0)

// butterfly: swap lane-bit L with the register bit distinguishing X0/X1
#define BFLY(L, X0, X1) {                                   \
    int t0_ = __shfl_xor((int)(X0), (L), 64);               \
    int t1_ = __shfl_xor((int)(X1), (L), 64);               \
    unsigned n0_ = (lane & (L)) ? (unsigned)t1_ : (X0);     \
    unsigned n1_ = (lane & (L)) ? (X1) : (unsigned)t0_;     \
    (X0) = n0_; (X1) = n1_; }

// ---- pre-pass 1: fy f32 -> bf16 (RNE), 8 elems per thread ----
__global__ __launch_bounds__(256) void cvt_bf16(const float* __restrict__ in,
                                                unsigned short* __restrict__ o16,
                                                int n8) {
    int i = blockIdx.x * 256 + threadIdx.x;
    if (i >= n8) return;
    const float4* p = (const float4*)(in + (size_t)i * 8);
    float4 a = p[0], b = p[1];
    *(uint4*)(o16 + (size_t)i * 8) =
        make_uint4(pk2(a.x, a.y), pk2(a.z, a.w), pk2(b.x, b.y), pk2(b.z, b.w));
}

// ---- pre-pass 2: pack weight fragments (MFMA lane order) + bias tables ----
// frag ids: 0..7 = W1[kb*4+f], 8..15 = W2, 16..19 = W3 (kb*2+f).
// lane (quad,c16) reg j holds W[perm(32kb+8quad+j), 16f + c16].
// W1 perm: kp<32 -> row 6+kp (fy); 32..37 -> rows 0..5 (y_j,y_i); 38 -> b1; else 0.
// bytes [20480,20736): b2tab[q*16+mb*4+r] = b2[16mb+4q+r]
// bytes [20736,20864): b3tab[q*8 +mb*4+r] = b3[16mb+4q+r]
__global__ __launch_bounds__(256) void pack_weights(
    const float* __restrict__ W1, const float* __restrict__ b1,
    const float* __restrict__ W2, const float* __restrict__ b2,
    const float* __restrict__ W3, const float* __restrict__ b3,
    unsigned short* __restrict__ wpack)
{
    int t = blockIdx.x * 256 + threadIdx.x;
    if (t < 20 * 64) {
        int f = t >> 6, lane = t & 63;
        int quad = lane >> 4, c16 = lane & 15;
        unsigned short v8[8];
        if (f < 8) {
            int kb = f >> 2, nb = f & 3;
            #pragma unroll
            for (int j = 0; j < 8; ++j) {
                int kp = kb * 32 + quad * 8 + j;
                int n  = nb * 16 + c16;
                float v;
                if (kp < 32)      v = W1[(6 + kp) * 64 + n];
                else if (kp < 38) v = W1[(kp - 32) * 64 + n];
                else if (kp == 38) v = b1[n];
                else              v = 0.f;
                v8[j] = bf16rne(v);
            }
        } else if (f < 16) {
            int kb = (f - 8) >> 2, nb = (f - 8) & 3;
            #pragma unroll
            for (int j = 0; j < 8; ++j) {
                int k = kb * 32 + quad * 8 + j;
                v8[j] = bf16rne(W2[k * 64 + nb * 16 + c16]);
            }
        } else {
            int kb = (f - 16) >> 1, nb = (f - 16) & 1;
            #pragma unroll
            for (int j = 0; j < 8; ++j) {
                int k = kb * 32 + quad * 8 + j;
                v8[j] = bf16rne(W3[k * 32 + nb * 16 + c16]);
            }
        }
        uint4 o;
        o.x = (unsigned)v8[0] | ((unsigned)v8[1] << 16);
        o.y = (unsigned)v8[2] | ((unsigned)v8[3] << 16);
        o.z = (unsigned)v8[4] | ((unsigned)v8[5] << 16);
        o.w = (unsigned)v8[6] | ((unsigned)v8[7] << 16);
        *(uint4*)(wpack + (size_t)t * 8) = o;
    } else if (t < 1344) {               // b2tab: 64 floats
        int idx = t - 1280;
        float* btab = (float*)(wpack + 10240);
        btab[idx] = b2[16 * ((idx >> 2) & 3) + 4 * (idx >> 4) + (idx & 3)];
    } else if (t < 1376) {               // b3tab: 32 floats
        int idx = t - 1344;
        float* btab = (float*)(wpack + 10240);
        btab[64 + idx] = b3[16 * ((idx >> 2) & 1) + 4 * (idx >> 3) + (idx & 3)];
    }
}

__global__ __launch_bounds__(256, 4) void it_mfma(
    const float* __restrict__ y, const unsigned short* __restrict__ fy16,
    const float* __restrict__ wts,
    const unsigned short* __restrict__ wpack,
    const int* __restrict__ nbr,
    float* __restrict__ out, int npts)
{
    __shared__ unsigned short wlds[10432];   // 20864 B: frags + bias tables

    const int tid  = threadIdx.x;
    const int lane = tid & 63;
    const int wv   = tid >> 6;
    const int quad = lane >> 4;
    const int c16  = lane & 15;
    const int wgid   = blockIdx.x * 4 + wv;
    const int nwaves = gridDim.x * 4;

    // block-cooperative weight+bias load (before any early exit)
    {
        const uint4* src = (const uint4*)wpack;
        uint4* dst = (uint4*)wlds;
        #pragma unroll
        for (int i = 0; i < 6; ++i) {
            int idx = tid + i * 256;
            if (idx < 1304) dst[idx] = src[idx];
        }
    }
    __syncthreads();
    if (wgid >= npts) return;

    const floatx4 fz = {0.f, 0.f, 0.f, 0.f};

    // ---- prologue: prefetch first point ----
    int p = wgid;
    int   e32 = nbr[p * 32 + (lane & 31)];
    float w32 = wts[e32];
    short8 a0c[2];
    float yjc[2][3] = {{0.f,0.f,0.f},{0.f,0.f,0.f}};
    {
        int j0 = __shfl(e32, c16), j1 = __shfl(e32, 16 + c16);
        a0c[0] = *(const short8*)(fy16 + (size_t)j0 * 32 + quad * 8);
        a0c[1] = *(const short8*)(fy16 + (size_t)j1 * 32 + quad * 8);
        if (quad == 0) {
            yjc[0][0] = y[3*j0]; yjc[0][1] = y[3*j0+1]; yjc[0][2] = y[3*j0+2];
            yjc[1][0] = y[3*j1]; yjc[1][1] = y[3*j1+1]; yjc[1][2] = y[3*j1+2];
        }
    }
    float yjn[2][3] = {{0.f,0.f,0.f},{0.f,0.f,0.f}};
    short8 a0n[2];
    float w32n = 0.f;

    unsigned woff = 0;   // asm barrier makes LDS reads loop-variant (anti-LICM)

    for (;;) {
        asm volatile("" : "+v"(woff));
        const unsigned short* wp = wlds + woff;
        const float* bp = (const float*)((const char*)wp + 20480);
        #define WFRAG(fid) (*(const short8*)(wp + (((fid) * 64 + lane) * 8)))

        const int pu = __builtin_amdgcn_readfirstlane(p);
        const int pn = p + nwaves;
        const bool last = (pn >= npts);
        const int pnc = last ? p : pn;
        int e32n = nbr[pnc * 32 + (lane & 31)];          // issue next-nbr early

        const float yi0 = y[3*pu], yi1 = y[3*pu+1], yi2 = y[3*pu+2];

        // per-lane bias vectors (broadcast LDS reads, loop-variant via bp)
        floatx4 b2v[4], b3v[2];
        #pragma unroll
        for (int mb = 0; mb < 4; ++mb)
            b2v[mb] = *(const floatx4*)(bp + quad * 16 + mb * 4);
        b3v[0] = *(const floatx4*)(bp + 64 + quad * 8);
        b3v[1] = *(const floatx4*)(bp + 64 + quad * 8 + 4);

        float vs0[4] = {0.f, 0.f, 0.f, 0.f};
        float vs1[4] = {0.f, 0.f, 0.f, 0.f};

        #pragma unroll
        for (int t = 0; t < 2; ++t) {
            // ---- B-frag kb=1 of agg^T: k=32..37 y-block, k=38 bias-one ----
            short8 a1 = {0,0,0,0,0,0,0,0};
            if (quad == 0) {
                union { short8 s; unsigned int u[4]; } cv;
                cv.u[0] = pk2(yjc[t][0], yjc[t][1]);
                cv.u[1] = pk2(yjc[t][2], yi0);
                cv.u[2] = pk2(yi1, yi2);
                cv.u[3] = pk2(1.0f, 0.0f);     // k=38: bias row multiplier
                a1 = cv.s;
            }
            // ---- layer 1 (transposed): D[m=hid, e], A=W1-frags, B=agg ----
            floatx4 acc[4];
            #pragma unroll
            for (int mb = 0; mb < 4; ++mb) {
                acc[mb] = MFMA16(WFRAG(mb),     a0c[t], fz);
                acc[mb] = MFMA16(WFRAG(4 + mb), a1,     acc[mb]);
            }
            // gelu (b1 already folded) + pack pairs (r0,r1)
            unsigned uu[8];
            #pragma unroll
            for (int mb = 0; mb < 4; ++mb)
                #pragma unroll
                for (int r1 = 0; r1 < 2; ++r1) {
                    f32x2 xin = {acc[mb][2*r1], acc[mb][2*r1+1]};
                    f32x2 g = gelu2(xin);
                    uu[mb*2 + r1] = pk2(g.x, g.y);
                }
            // register transpose: lane(q1,q0),reg(mb1,mb0,r1) ->
            //                     lane(mb0,q1),reg(kb=mb1,j2=q0,r1)
            BFLY(32, uu[0], uu[2]); BFLY(32, uu[1], uu[3]);
            BFLY(32, uu[4], uu[6]); BFLY(32, uu[5], uu[7]);
            BFLY(16, uu[0], uu[2]); BFLY(16, uu[1], uu[3]);
            BFLY(16, uu[4], uu[6]); BFLY(16, uu[5], uu[7]);
            short8 hb0, hb1;
            {
                union { unsigned u[4]; short8 s; } c0, c1;
                c0.u[0]=uu[0]; c0.u[1]=uu[1]; c0.u[2]=uu[2]; c0.u[3]=uu[3];
                c1.u[0]=uu[4]; c1.u[1]=uu[5]; c1.u[2]=uu[6]; c1.u[3]=uu[7];
                hb0 = c0.s; hb1 = c1.s;
            }
            // ---- layer 2 ----
            #pragma unroll
            for (int mb = 0; mb < 4; ++mb) {
                acc[mb] = MFMA16(WFRAG(8 + mb),  hb0, fz);
                acc[mb] = MFMA16(WFRAG(12 + mb), hb1, acc[mb]);
            }
            #pragma unroll
            for (int mb = 0; mb < 4; ++mb)
                #pragma unroll
                for (int r1 = 0; r1 < 2; ++r1) {
                    f32x2 xin = {acc[mb][2*r1]   + b2v[mb][2*r1],
                                 acc[mb][2*r1+1] + b2v[mb][2*r1+1]};
                    f32x2 g = gelu2(xin);
                    uu[mb*2 + r1] = pk2(g.x, g.y);
                }
            BFLY(32, uu[0], uu[2]); BFLY(32, uu[1], uu[3]);
            BFLY(32, uu[4], uu[6]); BFLY(32, uu[5], uu[7]);
            BFLY(16, uu[0], uu[2]); BFLY(16, uu[1], uu[3]);
            BFLY(16, uu[4], uu[6]); BFLY(16, uu[5], uu[7]);
            short8 gb0, gb1;
            {
                union { unsigned u[4]; short8 s; } c0, c1;
                c0.u[0]=uu[0]; c0.u[1]=uu[1]; c0.u[2]=uu[2]; c0.u[3]=uu[3];
                c1.u[0]=uu[4]; c1.u[1]=uu[5]; c1.u[2]=uu[6]; c1.u[3]=uu[7];
                gb0 = c0.s; gb1 = c1.s;
            }
            // ---- layer 3: D[m=outCh(32), e] ----
            floatx4 o0, o1;
            o0 = MFMA16(WFRAG(16), gb0, fz);
            o0 = MFMA16(WFRAG(18), gb1, o0);
            o1 = MFMA16(WFRAG(17), gb0, fz);
            o1 = MFMA16(WFRAG(19), gb1, o1);

            // ---- prefetch next point under the back half of t=0 ----
            if (t == 0) {
                int jn0 = __shfl(e32n, c16), jn1 = __shfl(e32n, 16 + c16);
                a0n[0] = *(const short8*)(fy16 + (size_t)jn0 * 32 + quad * 8);
                a0n[1] = *(const short8*)(fy16 + (size_t)jn1 * 32 + quad * 8);
                w32n = wts[e32n];
                if (quad == 0) {
                    yjn[0][0] = y[3*jn0]; yjn[0][1] = y[3*jn0+1]; yjn[0][2] = y[3*jn0+2];
                    yjn[1][0] = y[3*jn1]; yjn[1][1] = y[3*jn1+1]; yjn[1][2] = y[3*jn1+2];
                }
            }

            // ---- epilogue for this edge-tile: ch = 16mb + 4quad + r, e = c16 ----
            int   el = t * 16 + c16;
            int   je = __shfl(e32, el);
            float we = __shfl(w32, el);
            ushort4v fa = *(const ushort4v*)(fy16 + (size_t)je * 32 + 4 * quad);
            ushort4v fb = *(const ushort4v*)(fy16 + (size_t)je * 32 + 16 + 4 * quad);
            #pragma unroll
            for (int r = 0; r < 4; ++r) {
                vs0[r] = fmaf((o0[r] + b3v[0][r]) * bf16f(fa[r]), we, vs0[r]);
                vs1[r] = fmaf((o1[r] + b3v[1][r]) * bf16f(fb[r]), we, vs1[r]);
            }
        }
        #undef WFRAG

        // ---- reduce over the 16 edge-lanes (c16) and store ----
        #pragma unroll
        for (int r = 0; r < 4; ++r) {
            vs0[r] += __shfl_xor(vs0[r], 1, 64);
            vs0[r] += __shfl_xor(vs0[r], 2, 64);
            vs0[r] += __shfl_xor(vs0[r], 4, 64);
            vs0[r] += __shfl_xor(vs0[r], 8, 64);
            vs1[r] += __shfl_xor(vs1[r], 1, 64);
            vs1[r] += __shfl_xor(vs1[r], 2, 64);
            vs1[r] += __shfl_xor(vs1[r], 4, 64);
            vs1[r] += __shfl_xor(vs1[r], 8, 64);
        }
        if (c16 == 0) {
            *(float4*)(out + (size_t)pu * 32 + 4 * quad) =
                make_float4(vs0[0], vs0[1], vs0[2], vs0[3]);
            *(float4*)(out + (size_t)pu * 32 + 16 + 4 * quad) =
                make_float4(vs1[0], vs1[1], vs1[2], vs1[3]);
        }

        if (last) break;
        p = pn;
        e32 = e32n; w32 = w32n;
        a0c[0] = a0n[0]; a0c[1] = a0n[1];
        #pragma unroll
        for (int t = 0; t < 2; ++t)
            #pragma unroll
            for (int k = 0; k < 3; ++k) yjc[t][k] = yjn[t][k];
    }
}

extern "C" void kernel_launch(void* const* d_in, const int* in_sizes, int n_in,
                              void* d_out, int out_size, void* d_ws, size_t ws_size,
                              hipStream_t stream) {
    const float* y  = (const float*)d_in[0];
    const float* fy = (const float*)d_in[1];
    const float* wt = (const float*)d_in[2];
    const float* W1 = (const float*)d_in[3];
    const float* b1 = (const float*)d_in[4];
    const float* W2 = (const float*)d_in[5];
    const float* b2 = (const float*)d_in[6];
    const float* W3 = (const float*)d_in[7];
    const float* b3 = (const float*)d_in[8];
    const int* nbr  = (const int*)d_in[9];
    const int E = in_sizes[9];
    const int npts = E >> 5;              // K = 32 fixed
    float* out = (float*)d_out;

    // workspace: [0, 20864) packed frags + bias tables; [32768, ...) fy16
    unsigned short* wpack = (unsigned short*)d_ws;
    unsigned short* fy16  = (unsigned short*)((char*)d_ws + 32768);

    hipLaunchKernelGGL(pack_weights, dim3(6), dim3(256), 0, stream,
                       W1, b1, W2, b2, W3, b3, wpack);
    const int n8 = npts * 4;              // 8 floats per thread
    hipLaunchKernelGGL(cvt_bf16, dim3((n8 + 255) / 256), dim3(256), 0, stream,
                       fy, fy16, n8);

    // grid = measured residency x 256 CUs -> persistent, no straggler tail
    static int bpc = 0;
    if (bpc == 0) {
        hipOccupancyMaxActiveBlocksPerMultiprocessor(&bpc, it_mfma, 256, 0);
        if (bpc < 1) bpc = 4;
        if (bpc > 8) bpc = 8;
    }
    int grid = bpc * 256;                 // MI355X: 256 CUs
    hipLaunchKernelGGL(it_mfma, dim3(grid), dim3(256), 0, stream,
                       y, fy16, wt, wpack, nbr, out, npts);
}

// Round 6
// 205.339 us; speedup vs baseline: 1.0905x; 1.0905x over previous
//
#include <hip/hip_runtime.h>
#include <hip/hip_bf16.h>
#include <math.h>

// IntegralTransform via bf16 MFMA (16x16x32), v5 "permlane + DPP + layer-major":
//  - v4 post-mortem: __shfl_xor butterflies = ds_swizzle (DS pipe!) + cndmask;
//    DS ops/point ~146 and a longer serial chain -> v4 (134us) lost to v3 (118us).
//  - v5 transposes with v_permlane32/16_swap_b32 (pure VALU, 1 op per pair —
//    exact BFLY equivalent, verified element-wise), reduces with DPP row_ror/
//    quad_perm adds (zero DS), and goes layer-major over both edge-tiles so
//    each weight fragment is ds_read ONCE per point (40 -> 20 b128 reads).
//    a1 (y_j|y_i|bias) fragment is built at prefetch time, off critical path.
//  - DS ops/point ~146 -> ~34; serial DS chains ~6 -> ~1.
//  - biases b2/b3 read from LDS tables only where needed (short live ranges).

typedef __attribute__((ext_vector_type(8))) short short8;
typedef __attribute__((ext_vector_type(4))) float floatx4;
typedef __attribute__((ext_vector_type(2))) float f32x2;
typedef __attribute__((ext_vector_type(4))) unsigned short ushort4v;
typedef __attribute__((ext_vector_type(2))) unsigned int uint2v;

__device__ __forceinline__ unsigned short bf16rne(float f) {
    unsigned int u = __float_as_uint(f);
    u += 0x7fffu + ((u >> 16) & 1u);
    return (unsigned short)(u >> 16);
}
__device__ __forceinline__ unsigned int pk2(float a, float b) {
    union { __hip_bfloat162 h; unsigned int u; } cv;
    cv.h = __float22bfloat162_rn(make_float2(a, b));
    return cv.u;
}
__device__ __forceinline__ float bf16f(unsigned short u) {
    return __uint_as_float(((unsigned int)u) << 16);
}
// tanh-form gelu pair -> packed bf16x2.
__device__ __forceinline__ unsigned int gelu2pk(float x, float y) {
    float ux = x * fmaf(0.044715f * x, x, 1.0f);
    float uy = y * fmaf(0.044715f * y, y, 1.0f);
    float ex = __expf(1.5957691f * ux);
    float ey = __expf(1.5957691f * uy);
    float gx = fmaf(-x, __builtin_amdgcn_rcpf(ex + 1.0f), x);
    float gy = fmaf(-y, __builtin_amdgcn_rcpf(ey + 1.0f), y);
    return pk2(gx, gy);
}

#define MFMA16(a, b, c) __builtin_amdgcn_mfma_f32_16x16x32_bf16(a, b, c, 0, 0, 0)

// lane-bit<->reg-bit exchanges, pure VALU (no DS pipe):
#define PSWAP32(a, b) { uint2v r_ = __builtin_amdgcn_permlane32_swap((a), (b), false, false); (a) = r_[0]; (b) = r_[1]; }
#define PSWAP16(a, b) { uint2v r_ = __builtin_amdgcn_permlane16_swap((a), (b), false, false); (a) = r_[0]; (b) = r_[1]; }

// DPP sum step: x += x[src per ctrl] within 16-lane row. 0x128=row_ror:8,
// 0x124=row_ror:4, 0x4E=quad_perm xor2, 0xB1=quad_perm xor1.
template<int CTRL>
__device__ __forceinline__ float dpp_add(float x) {
    int y = __builtin_amdgcn_update_dpp(0, __float_as_int(x), CTRL, 0xF, 0xF, true);
    return x + __int_as_float(y);
}
__device__ __forceinline__ float row16_sum(float x) {
    x = dpp_add<0x128>(x);
    x = dpp_add<0x124>(x);
    x = dpp_add<0x4E>(x);
    x = dpp_add<0xB1>(x);
    return x;
}

// ---- pre-pass 1: fy f32 -> bf16 (RNE), 8 elems per thread ----
__global__ __launch_bounds__(256) void cvt_bf16(const float* __restrict__ in,
                                                unsigned short* __restrict__ o16,
                                                int n8) {
    int i = blockIdx.x * 256 + threadIdx.x;
    if (i >= n8) return;
    const float4* p = (const float4*)(in + (size_t)i * 8);
    float4 a = p[0], b = p[1];
    *(uint4*)(o16 + (size_t)i * 8) =
        make_uint4(pk2(a.x, a.y), pk2(a.z, a.w), pk2(b.x, b.y), pk2(b.z, b.w));
}

// ---- pre-pass 2: pack weight fragments (MFMA lane order) + bias tables ----
// frag ids: 0..7 = W1[kb*4+f], 8..15 = W2, 16..19 = W3 (kb*2+f).
// lane (quad,c16) reg j holds W[perm(32kb+8quad+j), 16f + c16].
// W1 perm: kp<32 -> row 6+kp (fy); 32..37 -> rows 0..5 (y_j,y_i); 38 -> b1; else 0.
// bytes [20480,20736): b2tab[q*16+mb*4+r] = b2[16mb+4q+r]
// bytes [20736,20864): b3tab[q*8 +mb*4+r] = b3[16mb+4q+r]
__global__ __launch_bounds__(256) void pack_weights(
    const float* __restrict__ W1, const float* __restrict__ b1,
    const float* __restrict__ W2, const float* __restrict__ b2,
    const float* __restrict__ W3, const float* __restrict__ b3,
    unsigned short* __restrict__ wpack)
{
    int t = blockIdx.x * 256 + threadIdx.x;
    if (t < 20 * 64) {
        int f = t >> 6, lane = t & 63;
        int quad = lane >> 4, c16 = lane & 15;
        unsigned short v8[8];
        if (f < 8) {
            int kb = f >> 2, nb = f & 3;
            #pragma unroll
            for (int j = 0; j < 8; ++j) {
                int kp = kb * 32 + quad * 8 + j;
                int n  = nb * 16 + c16;
                float v;
                if (kp < 32)      v = W1[(6 + kp) * 64 + n];
                else if (kp < 38) v = W1[(kp - 32) * 64 + n];
                else if (kp == 38) v = b1[n];
                else              v = 0.f;
                v8[j] = bf16rne(v);
            }
        } else if (f < 16) {
            int kb = (f - 8) >> 2, nb = (f - 8) & 3;
            #pragma unroll
            for (int j = 0; j < 8; ++j) {
                int k = kb * 32 + quad * 8 + j;
                v8[j] = bf16rne(W2[k * 64 + nb * 16 + c16]);
            }
        } else {
            int kb = (f - 16) >> 1, nb = (f - 16) & 1;
            #pragma unroll
            for (int j = 0; j < 8; ++j) {
                int k = kb * 32 + quad * 8 + j;
                v8[j] = bf16rne(W3[k * 32 + nb * 16 + c16]);
            }
        }
        uint4 o;
        o.x = (unsigned)v8[0] | ((unsigned)v8[1] << 16);
        o.y = (unsigned)v8[2] | ((unsigned)v8[3] << 16);
        o.z = (unsigned)v8[4] | ((unsigned)v8[5] << 16);
        o.w = (unsigned)v8[6] | ((unsigned)v8[7] << 16);
        *(uint4*)(wpack + (size_t)t * 8) = o;
    } else if (t < 1344) {               // b2tab: 64 floats
        int idx = t - 1280;
        float* btab = (float*)(wpack + 10240);
        btab[idx] = b2[16 * ((idx >> 2) & 3) + 4 * (idx >> 4) + (idx & 3)];
    } else if (t < 1376) {               // b3tab: 32 floats
        int idx = t - 1344;
        float* btab = (float*)(wpack + 10240);
        btab[64 + idx] = b3[16 * ((idx >> 2) & 1) + 4 * (idx >> 3) + (idx & 3)];
    }
}

__global__ __launch_bounds__(256, 4) void it_mfma(
    const float* __restrict__ y, const unsigned short* __restrict__ fy16,
    const float* __restrict__ wts,
    const unsigned short* __restrict__ wpack,
    const int* __restrict__ nbr,
    float* __restrict__ out, int npts)
{
    __shared__ unsigned short wlds[10432];   // 20864 B: frags + bias tables

    const int tid  = threadIdx.x;
    const int lane = tid & 63;
    const int wv   = tid >> 6;
    const int quad = lane >> 4;
    const int c16  = lane & 15;
    const int wgid   = blockIdx.x * 4 + wv;
    const int nwaves = gridDim.x * 4;

    // block-cooperative weight+bias load (before any early exit)
    {
        const uint4* src = (const uint4*)wpack;
        uint4* dst = (uint4*)wlds;
        #pragma unroll
        for (int i = 0; i < 6; ++i) {
            int idx = tid + i * 256;
            if (idx < 1304) dst[idx] = src[idx];
        }
    }
    __syncthreads();
    if (wgid >= npts) return;

    const floatx4 fz = {0.f, 0.f, 0.f, 0.f};
    const short8 s8z = {0,0,0,0,0,0,0,0};

    // ---- prologue: fetch first point's inputs + build a1 frags ----
    int p = wgid;
    int   e32 = nbr[p * 32 + (lane & 31)];
    float w32 = wts[e32];
    short8 a0c[2], a1c[2];
    {
        const int pu0 = __builtin_amdgcn_readfirstlane(p);
        int j0 = __shfl(e32, c16), j1 = __shfl(e32, 16 + c16);
        a0c[0] = *(const short8*)(fy16 + (size_t)j0 * 32 + quad * 8);
        a0c[1] = *(const short8*)(fy16 + (size_t)j1 * 32 + quad * 8);
        a1c[0] = s8z; a1c[1] = s8z;
        if (quad == 0) {
            float xa = y[3*pu0], xb = y[3*pu0+1], xc = y[3*pu0+2];
            float ja = y[3*j0], jb = y[3*j0+1], jc = y[3*j0+2];
            float ka = y[3*j1], kb = y[3*j1+1], kc = y[3*j1+2];
            union { short8 s; unsigned int u[4]; } c0, c1;
            c0.u[0] = pk2(ja, jb); c0.u[1] = pk2(jc, xa);
            c0.u[2] = pk2(xb, xc); c0.u[3] = pk2(1.0f, 0.0f);
            c1.u[0] = pk2(ka, kb); c1.u[1] = pk2(kc, xa);
            c1.u[2] = pk2(xb, xc); c1.u[3] = pk2(1.0f, 0.0f);
            a1c[0] = c0.s; a1c[1] = c1.s;
        }
    }
    short8 a0n[2], a1n[2];
    float w32n = 0.f;

    unsigned woff = 0;   // asm barrier keeps LDS frag reads loop-variant
                         // (anti-LICM: hoisting 20 frags into regs = v2 spill)

    for (;;) {
        asm volatile("" : "+v"(woff));
        const unsigned short* wp = wlds + woff;
        const float* bp = (const float*)((const char*)wp + 20480);
        #define WFRAG(fid) (*(const short8*)(wp + (((fid) * 64 + lane) * 8)))

        const int pu = __builtin_amdgcn_readfirstlane(p);
        const int pn = p + nwaves;
        const bool last = (pn >= npts);
        const int pncu = __builtin_amdgcn_readfirstlane(last ? p : pn);
        int e32n = nbr[pncu * 32 + (lane & 31)];         // issue next-nbr early

        // ---- layer 1, both tiles (each W1 frag read once) ----
        floatx4 acc0[4], acc1[4];
        #pragma unroll
        for (int mb = 0; mb < 4; ++mb) {
            short8 w = WFRAG(mb);
            acc0[mb] = MFMA16(w, a0c[0], fz);
            acc1[mb] = MFMA16(w, a0c[1], fz);
        }
        #pragma unroll
        for (int mb = 0; mb < 4; ++mb) {
            short8 w = WFRAG(4 + mb);
            acc0[mb] = MFMA16(w, a1c[0], acc0[mb]);
            acc1[mb] = MFMA16(w, a1c[1], acc1[mb]);
        }
        // gelu (b1 folded into MFMA) + pack
        unsigned u0[8], u1[8];
        #pragma unroll
        for (int mb = 0; mb < 4; ++mb) {
            u0[mb*2]   = gelu2pk(acc0[mb][0], acc0[mb][1]);
            u0[mb*2+1] = gelu2pk(acc0[mb][2], acc0[mb][3]);
            u1[mb*2]   = gelu2pk(acc1[mb][0], acc1[mb][1]);
            u1[mb*2+1] = gelu2pk(acc1[mb][2], acc1[mb][3]);
        }
        // register transpose, pure VALU
        PSWAP32(u0[0], u0[2]); PSWAP32(u0[1], u0[3]);
        PSWAP32(u0[4], u0[6]); PSWAP32(u0[5], u0[7]);
        PSWAP16(u0[0], u0[2]); PSWAP16(u0[1], u0[3]);
        PSWAP16(u0[4], u0[6]); PSWAP16(u0[5], u0[7]);
        PSWAP32(u1[0], u1[2]); PSWAP32(u1[1], u1[3]);
        PSWAP32(u1[4], u1[6]); PSWAP32(u1[5], u1[7]);
        PSWAP16(u1[0], u1[2]); PSWAP16(u1[1], u1[3]);
        PSWAP16(u1[4], u1[6]); PSWAP16(u1[5], u1[7]);
        short8 hb00, hb10, hb01, hb11;
        {
            union { unsigned u[4]; short8 s; } c;
            c.u[0]=u0[0]; c.u[1]=u0[1]; c.u[2]=u0[2]; c.u[3]=u0[3]; hb00 = c.s;
            c.u[0]=u0[4]; c.u[1]=u0[5]; c.u[2]=u0[6]; c.u[3]=u0[7]; hb10 = c.s;
            c.u[0]=u1[0]; c.u[1]=u1[1]; c.u[2]=u1[2]; c.u[3]=u1[3]; hb01 = c.s;
            c.u[0]=u1[4]; c.u[1]=u1[5]; c.u[2]=u1[6]; c.u[3]=u1[7]; hb11 = c.s;
        }

        // ---- prefetch next point (hidden under layers 2/3) ----
        {
            int jn0 = __shfl(e32n, c16), jn1 = __shfl(e32n, 16 + c16);
            a0n[0] = *(const short8*)(fy16 + (size_t)jn0 * 32 + quad * 8);
            a0n[1] = *(const short8*)(fy16 + (size_t)jn1 * 32 + quad * 8);
            w32n = wts[e32n];
            a1n[0] = s8z; a1n[1] = s8z;
            if (quad == 0) {
                float xa = y[3*pncu], xb = y[3*pncu+1], xc = y[3*pncu+2];
                float ja = y[3*jn0], jb = y[3*jn0+1], jc = y[3*jn0+2];
                float ka = y[3*jn1], kb = y[3*jn1+1], kc = y[3*jn1+2];
                union { short8 s; unsigned int u[4]; } c0, c1;
                c0.u[0] = pk2(ja, jb); c0.u[1] = pk2(jc, xa);
                c0.u[2] = pk2(xb, xc); c0.u[3] = pk2(1.0f, 0.0f);
                c1.u[0] = pk2(ka, kb); c1.u[1] = pk2(kc, xa);
                c1.u[2] = pk2(xb, xc); c1.u[3] = pk2(1.0f, 0.0f);
                a1n[0] = c0.s; a1n[1] = c1.s;
            }
        }

        // ---- layer 2, both tiles ----
        #pragma unroll
        for (int mb = 0; mb < 4; ++mb) {
            short8 w = WFRAG(8 + mb);
            acc0[mb] = MFMA16(w, hb00, fz);
            acc1[mb] = MFMA16(w, hb01, fz);
        }
        #pragma unroll
        for (int mb = 0; mb < 4; ++mb) {
            short8 w = WFRAG(12 + mb);
            acc0[mb] = MFMA16(w, hb10, acc0[mb]);
            acc1[mb] = MFMA16(w, hb11, acc1[mb]);
        }
        #pragma unroll
        for (int mb = 0; mb < 4; ++mb) {
            floatx4 b2v = *(const floatx4*)(bp + quad * 16 + mb * 4);
            u0[mb*2]   = gelu2pk(acc0[mb][0] + b2v[0], acc0[mb][1] + b2v[1]);
            u0[mb*2+1] = gelu2pk(acc0[mb][2] + b2v[2], acc0[mb][3] + b2v[3]);
            u1[mb*2]   = gelu2pk(acc1[mb][0] + b2v[0], acc1[mb][1] + b2v[1]);
            u1[mb*2+1] = gelu2pk(acc1[mb][2] + b2v[2], acc1[mb][3] + b2v[3]);
        }
        PSWAP32(u0[0], u0[2]); PSWAP32(u0[1], u0[3]);
        PSWAP32(u0[4], u0[6]); PSWAP32(u0[5], u0[7]);
        PSWAP16(u0[0], u0[2]); PSWAP16(u0[1], u0[3]);
        PSWAP16(u0[4], u0[6]); PSWAP16(u0[5], u0[7]);
        PSWAP32(u1[0], u1[2]); PSWAP32(u1[1], u1[3]);
        PSWAP32(u1[4], u1[6]); PSWAP32(u1[5], u1[7]);
        PSWAP16(u1[0], u1[2]); PSWAP16(u1[1], u1[3]);
        PSWAP16(u1[4], u1[6]); PSWAP16(u1[5], u1[7]);
        short8 gb00, gb10, gb01, gb11;
        {
            union { unsigned u[4]; short8 s; } c;
            c.u[0]=u0[0]; c.u[1]=u0[1]; c.u[2]=u0[2]; c.u[3]=u0[3]; gb00 = c.s;
            c.u[0]=u0[4]; c.u[1]=u0[5]; c.u[2]=u0[6]; c.u[3]=u0[7]; gb10 = c.s;
            c.u[0]=u1[0]; c.u[1]=u1[1]; c.u[2]=u1[2]; c.u[3]=u1[3]; gb01 = c.s;
            c.u[0]=u1[4]; c.u[1]=u1[5]; c.u[2]=u1[6]; c.u[3]=u1[7]; gb11 = c.s;
        }

        // ---- layer 3, both tiles (each W3 frag read once) ----
        floatx4 o00, o10, o01, o11;
        { short8 w = WFRAG(16); o00 = MFMA16(w, gb00, fz); o01 = MFMA16(w, gb01, fz); }
        { short8 w = WFRAG(18); o00 = MFMA16(w, gb10, o00); o01 = MFMA16(w, gb11, o01); }
        { short8 w = WFRAG(17); o10 = MFMA16(w, gb00, fz); o11 = MFMA16(w, gb01, fz); }
        { short8 w = WFRAG(19); o10 = MFMA16(w, gb10, o10); o11 = MFMA16(w, gb11, o11); }

        floatx4 b3v0 = *(const floatx4*)(bp + 64 + quad * 8);
        floatx4 b3v1 = *(const floatx4*)(bp + 64 + quad * 8 + 4);

        // ---- epilogue: ch = 16mb + 4quad + r, edge = c16 (t0) / 16+c16 (t1) ----
        float vs0[4] = {0.f, 0.f, 0.f, 0.f};
        float vs1[4] = {0.f, 0.f, 0.f, 0.f};
        {
            int   je = __shfl(e32, c16);
            float we = __shfl(w32, c16);
            ushort4v fa = *(const ushort4v*)(fy16 + (size_t)je * 32 + 4 * quad);
            ushort4v fb = *(const ushort4v*)(fy16 + (size_t)je * 32 + 16 + 4 * quad);
            #pragma unroll
            for (int r = 0; r < 4; ++r) {
                vs0[r] = fmaf((o00[r] + b3v0[r]) * bf16f(fa[r]), we, vs0[r]);
                vs1[r] = fmaf((o10[r] + b3v1[r]) * bf16f(fb[r]), we, vs1[r]);
            }
        }
        {
            int   je = __shfl(e32, 16 + c16);
            float we = __shfl(w32, 16 + c16);
            ushort4v fa = *(const ushort4v*)(fy16 + (size_t)je * 32 + 4 * quad);
            ushort4v fb = *(const ushort4v*)(fy16 + (size_t)je * 32 + 16 + 4 * quad);
            #pragma unroll
            for (int r = 0; r < 4; ++r) {
                vs0[r] = fmaf((o01[r] + b3v0[r]) * bf16f(fa[r]), we, vs0[r]);
                vs1[r] = fmaf((o11[r] + b3v1[r]) * bf16f(fb[r]), we, vs1[r]);
            }
        }
        #undef WFRAG

        // ---- reduce over the 16 edge-lanes via DPP (no DS ops) and store ----
        #pragma unroll
        for (int r = 0; r < 4; ++r) {
            vs0[r] = row16_sum(vs0[r]);
            vs1[r] = row16_sum(vs1[r]);
        }
        if (c16 == 0) {
            *(float4*)(out + (size_t)pu * 32 + 4 * quad) =
                make_float4(vs0[0], vs0[1], vs0[2], vs0[3]);
            *(float4*)(out + (size_t)pu * 32 + 16 + 4 * quad) =
                make_float4(vs1[0], vs1[1], vs1[2], vs1[3]);
        }

        if (last) break;
        p = pn;
        e32 = e32n; w32 = w32n;
        a0c[0] = a0n[0]; a0c[1] = a0n[1];
        a1c[0] = a1n[0]; a1c[1] = a1n[1];
    }
}

extern "C" void kernel_launch(void* const* d_in, const int* in_sizes, int n_in,
                              void* d_out, int out_size, void* d_ws, size_t ws_size,
                              hipStream_t stream) {
    const float* y  = (const float*)d_in[0];
    const float* fy = (const float*)d_in[1];
    const float* wt = (const float*)d_in[2];
    const float* W1 = (const float*)d_in[3];
    const float* b1 = (const float*)d_in[4];
    const float* W2 = (const float*)d_in[5];
    const float* b2 = (const float*)d_in[6];
    const float* W3 = (const float*)d_in[7];
    const float* b3 = (const float*)d_in[8];
    const int* nbr  = (const int*)d_in[9];
    const int E = in_sizes[9];
    const int npts = E >> 5;              // K = 32 fixed
    float* out = (float*)d_out;

    // workspace: [0, 20864) packed frags + bias tables; [32768, ...) fy16
    unsigned short* wpack = (unsigned short*)d_ws;
    unsigned short* fy16  = (unsigned short*)((char*)d_ws + 32768);

    hipLaunchKernelGGL(pack_weights, dim3(6), dim3(256), 0, stream,
                       W1, b1, W2, b2, W3, b3, wpack);
    const int n8 = npts * 4;              // 8 floats per thread
    hipLaunchKernelGGL(cvt_bf16, dim3((n8 + 255) / 256), dim3(256), 0, stream,
                       fy, fy16, n8);

    // grid = measured residency x 256 CUs -> persistent, no straggler tail
    static int bpc = 0;
    if (bpc == 0) {
        hipOccupancyMaxActiveBlocksPerMultiprocessor(&bpc, it_mfma, 256, 0);
        if (bpc < 1) bpc = 4;
        if (bpc > 8) bpc = 8;
    }
    int grid = bpc * 256;                 // MI355X: 256 CUs
    hipLaunchKernelGGL(it_mfma, dim3(grid), dim3(256), 0, stream,
                       y, fy16, wt, wpack, nbr, out, npts);
}